// Round 10
// baseline (268.586 us; speedup 1.0000x reference)
//
#include <hip/hip_runtime.h>
#include <climits>

// StreamingRhythmProjector: B=4096 rows x U=2048 units.
// R17: zero-barrier wave-per-row + FIT-IN-64-VGPR design (no carry at all).
// Evidence: R14/R15/R16 all show VGPR_Count=64 exactly — hipcc's allocator
// TARGETS 64 regs (occupancy heuristic; launch_bounds min-waves doesn't
// stop it) and spills anything above (R16: ~38 MB scratch writes despite
// fully named SSA variables). Fighting the allocator failed twice.
// R17 stops exceeding the target:
//  - pass 1: sums ONLY (no per-element carry), named 2-deep pipeline regs.
//  - pass 2: RE-READS the row via the same named pipeline and recomputes
//    sr/sc before scaling + store. Inputs total ~136 MB < 256 MB L3, so
//    re-reads hit Infinity Cache; FETCH_SIZE (HBM-only) should not grow.
//  - live state ~47-55 floats <= 64 -> allocator's 64-target = zero spill.
// Keeps: zero __syncthreads, zero LDS, predicated loads, early-exit open
// scan, per-wave tail. Free-run BW (R14/R16): 2.7-3.0 TB/s vs 2.35 convoy.
// Predictions: WRITE ~99 MB (no-spill discriminator), FETCH 45-55 MB
// (>=75 => L3 miss on re-read), VGPR<=64 no scratch, dur 46-55us.

constexpr int UNITS = 2048;
constexpr int BLOCK = 256;
constexpr int ROWS_PER_BLOCK = 4;  // one row per wave

typedef float f32x4 __attribute__((ext_vector_type(4)));

static __device__ __forceinline__ float waveSum(float v) {
#pragma unroll
  for (int m = 1; m < 64; m <<= 1) v += __shfl_xor(v, m, 64);
  return v;  // all lanes hold the sum
}

// Load chunk c (4 arrays x f32x4) into NAMED variables. Zero if masked out.
#define LOADC(c, A, L, P, Bv)                                         \
  {                                                                   \
    const int e_ = (c) * 256 + 4 * ln;                                \
    if (e_ < visible) {                                               \
      A  = *(const f32x4*)(dur_anchor   + base + e_);                 \
      L  = *(const f32x4*)(dur_logratio + base + e_);                 \
      P  = *(const f32x4*)(pause_weight + base + e_);                 \
      Bv = *(const f32x4*)(boundary     + base + e_);                 \
    } else {                                                          \
      A = z4; L = z4; P = z4; Bv = z4;                                \
    }                                                                 \
  }

// Pass-1 consume: accumulate the two sums only (no carry).
#define SUM1(j, eb_, A, L, P, Bv)                                     \
  {                                                                   \
    const float m_ = ((eb_) + (j) < visible) ? 1.0f : 0.0f;           \
    const float a_ = fmaxf((A)[j], 1.0f);                             \
    sum_sr += fmaxf(fminf(a_ * __expf((L)[j]), 3.0f * a_), 1.0f) * m_;\
    sum_sc += fmaxf((P)[j], 0.0f) * (0.5f + (Bv)[j]) * m_;            \
  }

#define SUMC(c, A, L, P, Bv)                                          \
  {                                                                   \
    const int eb_ = (c) * 256 + 4 * ln;                               \
    SUM1(0, eb_, A, L, P, Bv)                                         \
    SUM1(1, eb_, A, L, P, Bv)                                         \
    SUM1(2, eb_, A, L, P, Bv)                                         \
    SUM1(3, eb_, A, L, P, Bv)                                         \
  }

// Pass-2 consume: recompute sr/sc, scale, store 3 outputs.
#define OUT1(j, eb_, A, L, P, Bv, s4, q4, e4)                         \
  {                                                                   \
    const float m_ = ((eb_) + (j) < visible) ? 1.0f : 0.0f;           \
    const float a_ = fmaxf((A)[j], 1.0f);                             \
    const float srv =                                                 \
        fmaxf(fminf(a_ * __expf((L)[j]), 3.0f * a_), 1.0f) * m_;      \
    const float scv = fmaxf((P)[j], 0.0f) * (0.5f + (Bv)[j]) * m_;    \
    const float sp_ = srv * sscale;                                   \
    const float pa_ = usefb ? (m_ * fbw) : (scv * pscale);            \
    s4[j] = sp_;                                                      \
    q4[j] = pa_;                                                      \
    e4[j] = sp_ + pa_;                                                \
  }

#define OUTC(c, A, L, P, Bv)                                          \
  {                                                                   \
    const int eb_ = (c) * 256 + 4 * ln;                               \
    f32x4 s4, q4, e4;                                                 \
    OUT1(0, eb_, A, L, P, Bv, s4, q4, e4)                             \
    OUT1(1, eb_, A, L, P, Bv, s4, q4, e4)                             \
    OUT1(2, eb_, A, L, P, Bv, s4, q4, e4)                             \
    OUT1(3, eb_, A, L, P, Bv, s4, q4, e4)                             \
    *(f32x4*)(out_speech + base + eb_) = s4;                          \
    *(f32x4*)(out_pause  + base + eb_) = q4;                          \
    *(f32x4*)(out_eff    + base + eb_) = e4;                          \
  }

__global__ __launch_bounds__(BLOCK, 4) void rhythm_kernel(
    const float* __restrict__ dur_anchor,    // [B,U]
    const float* __restrict__ unit_mask,     // [B,U] prefix mask (0/1)
    const float* __restrict__ speech_budget, // [B]
    const float* __restrict__ pause_budget,  // [B]
    const float* __restrict__ dur_logratio,  // [B,U]
    const float* __restrict__ pause_weight,  // [B,U]
    const float* __restrict__ boundary,      // [B,U]
    const float* __restrict__ phase_ptr,     // [B]
    const float* __restrict__ backlog,       // [B]
    const float* __restrict__ clock_delta,   // [B]
    const int*   __restrict__ commit_front,  // [B]
    const int*   __restrict__ open_run,      // [B,U]
    float* __restrict__ out,                 // f32, 3*B*U + 4*B
    int B) {
  const int t = threadIdx.x;
  const int wv = t >> 6, ln = t & 63;
  const int row = blockIdx.x * ROWS_PER_BLOCK + wv;
  if (row >= B) return;  // whole-wave uniform; no barriers anywhere
  const size_t base = (size_t)row * UNITS;
  const f32x4 z4 = {0.f, 0.f, 0.f, 0.f};

  // per-row scalars
  const int prev = commit_front[row];
  const float sb = speech_budget[row];
  const float pb = pause_budget[row];

  // ---- probe `visible` from the prefix mask ----
  int visible;
  {
    const float v1 = unit_mask[base + 64 * ((ln < 32) ? ln : 0) + 63];
    const int c1 = __popcll(__ballot((ln < 32) && (v1 > 0.5f)));
    if (c1 == 32) {
      visible = 2048;
    } else {
      const int s = 64 * c1;                       // s <= 1984, s+63 <= 2047
      const float v2 = unit_mask[base + s + ln];
      visible = s + __popcll(__ballot(v2 > 0.5f));
    }
  }

  // ---- early-exit scan for first open index in [0, visible) ----
  int min_open = INT_MAX;
  for (int cs = 0; cs < visible; cs += 256) {
    const int e = cs + 4 * ln;                     // e+3 <= 2047 always
    int4 o4 = make_int4(0, 0, 0, 0);
    if (e < visible) o4 = *(const int4*)(open_run + base + e);
    int lm = INT_MAX;
    if (o4.w > 0 && e + 3 < visible) lm = e + 3;
    if (o4.z > 0 && e + 2 < visible) lm = e + 2;
    if (o4.y > 0 && e + 1 < visible) lm = e + 1;
    if (o4.x > 0 && e < visible) lm = e;
    const unsigned long long bb = __ballot(lm != INT_MAX);
    if (bb) {  // lanes ascend in idx; first set lane holds the chunk min
      min_open = __shfl(lm, (int)__ffsll(bb) - 1, 64);
      break;
    }
  }

  // ---- commit candidate + bval (issued before pass 1; resolves under it) --
  const int closed = (min_open == INT_MAX) ? visible : min_open;
  const int cand0 = min(max(visible - 2, 0), closed);  // TAIL_HOLD_UNITS
  const float bval = boundary[base + min(max(cand0 - 1, 0), UNITS - 1)];

  // ---- named 2-deep pipeline registers (shared by both passes) ----
  f32x4 A0, L0, P0, B0, A1, L1, P1, B1;
  float sum_sr = 0.f, sum_sc = 0.f;

  // ---- pass 1: sums only ----
  LOADC(0, A0, L0, P0, B0)
  LOADC(1, A1, L1, P1, B1)
  { f32x4 a = A0, l = L0, p = P0, b = B0; LOADC(2, A0, L0, P0, B0) SUMC(0, a, l, p, b) }
  { f32x4 a = A1, l = L1, p = P1, b = B1; LOADC(3, A1, L1, P1, B1) SUMC(1, a, l, p, b) }
  { f32x4 a = A0, l = L0, p = P0, b = B0; LOADC(4, A0, L0, P0, B0) SUMC(2, a, l, p, b) }
  { f32x4 a = A1, l = L1, p = P1, b = B1; LOADC(5, A1, L1, P1, B1) SUMC(3, a, l, p, b) }
  { f32x4 a = A0, l = L0, p = P0, b = B0; LOADC(6, A0, L0, P0, B0) SUMC(4, a, l, p, b) }
  { f32x4 a = A1, l = L1, p = P1, b = B1; LOADC(7, A1, L1, P1, B1) SUMC(5, a, l, p, b) }
  SUMC(6, A0, L0, P0, B0)
  SUMC(7, A1, L1, P1, B1)

  // ---- totals: pure in-wave reduction (NO barrier, NO LDS) ----
  const float ts = waveSum(sum_sr);
  const float tc = waveSum(sum_sc);
  const float tm = (float)visible;  // sum of prefix mask, exact

  // ---- commit frontier finalize ----
  int cand = cand0;
  if (cand0 > 0 && cand0 < visible && bval < 0.45f)   // BOUNDARY_COMMIT_THRESHOLD
    cand = max(prev, cand0 - 1);
  const int commit = max(prev, cand);

  const float sscale = sb / fmaxf(ts, 1e-6f);
  const bool usefb = !(tc > 0.0f);
  const float pscale = pb / fmaxf(tc, 1e-6f);
  const float fbw = pb / fmaxf(tm, 1.0f);
  // analytic effective total (linearity): Sum eff = sscale*ts + pscale*tc
  const float eff_tot = usefb ? (sscale * ts + fbw * tm) : (sscale * ts + pscale * tc);

  // ---- pass 2: re-read (L3-hot), recompute, scale, store ----
  float* __restrict__ out_speech = out;
  float* __restrict__ out_pause  = out + (size_t)B * UNITS;
  float* __restrict__ out_eff    = out + 2 * (size_t)B * UNITS;

  LOADC(0, A0, L0, P0, B0)
  LOADC(1, A1, L1, P1, B1)
  { f32x4 a = A0, l = L0, p = P0, b = B0; LOADC(2, A0, L0, P0, B0) OUTC(0, a, l, p, b) }
  { f32x4 a = A1, l = L1, p = P1, b = B1; LOADC(3, A1, L1, P1, B1) OUTC(1, a, l, p, b) }
  { f32x4 a = A0, l = L0, p = P0, b = B0; LOADC(4, A0, L0, P0, B0) OUTC(2, a, l, p, b) }
  { f32x4 a = A1, l = L1, p = P1, b = B1; LOADC(5, A1, L1, P1, B1) OUTC(3, a, l, p, b) }
  { f32x4 a = A0, l = L0, p = P0, b = B0; LOADC(6, A0, L0, P0, B0) OUTC(4, a, l, p, b) }
  { f32x4 a = A1, l = L1, p = P1, b = B1; LOADC(7, A1, L1, P1, B1) OUTC(5, a, l, p, b) }
  OUTC(6, A0, L0, P0, B0)
  OUTC(7, A1, L1, P1, B1)

  // ---- per-wave tail: tiny [prev,commit) range sums (cache-hot re-read) ----
  float src_rng = 0.f, eff_rng = 0.f;
  if (commit > prev) {
    for (int i = prev + ln; i < commit; i += 64) {     // all i < visible here
      const float a = dur_anchor[base + i];
      const float l = dur_logratio[base + i];
      const float p = pause_weight[base + i];
      const float bo = boundary[base + i];
      src_rng += a;
      const float aa = fmaxf(a, 1.0f);
      const float sr = fmaxf(fminf(aa * __expf(l), 3.0f * aa), 1.0f);
      const float sc = fmaxf(p, 0.0f) * (0.5f + bo);
      eff_rng += sr * sscale + (usefb ? fbw : sc * pscale);
    }
  }
  const float srcp = waveSum(src_rng);
  const float execp = waveSum(eff_rng);

  if (ln == 0) {
    const float pp = phase_ptr[row];
    const float bl = backlog[row];
    const float cd = clock_delta[row];
    const bool adv = commit > prev;
    const float nclock = adv ? (cd + (execp - srcp)) : cd;
    const float nback = adv ? fmaxf(nclock, 0.0f) : bl;
    const float vt = fmaxf(eff_tot, 1.0f);
    const float nphase =
        adv ? fminf(fmaxf(pp + execp / vt, 0.0f), 1.0f) : pp;
    const size_t o = 3 * (size_t)B * UNITS;
    out[o + row] = (float)commit;
    out[o + (size_t)B + row] = nphase;
    out[o + 2 * (size_t)B + row] = nback;
    out[o + 3 * (size_t)B + row] = nclock;
  }
}

extern "C" void kernel_launch(void* const* d_in, const int* in_sizes, int n_in,
                              void* d_out, int out_size, void* d_ws, size_t ws_size,
                              hipStream_t stream) {
  const int B = in_sizes[7];  // phase_ptr length
  const int nb = (B + ROWS_PER_BLOCK - 1) / ROWS_PER_BLOCK;
  rhythm_kernel<<<dim3(nb), dim3(BLOCK), 0, stream>>>(
      (const float*)d_in[0],   // dur_anchor_src
      (const float*)d_in[1],   // unit_mask
      (const float*)d_in[2],   // speech_budget_win
      (const float*)d_in[3],   // pause_budget_win
      (const float*)d_in[4],   // dur_logratio_unit
      (const float*)d_in[5],   // pause_weight_unit
      (const float*)d_in[6],   // boundary_latent
      (const float*)d_in[7],   // phase_ptr
      (const float*)d_in[8],   // backlog
      (const float*)d_in[9],   // clock_delta
      (const int*)d_in[10],    // commit_frontier
      (const int*)d_in[11],    // open_run_mask
      (float*)d_out, B);
}